// Round 6
// baseline (318.061 us; speedup 1.0000x reference)
//
#include <hip/hip_runtime.h>

#define H 2048
#define W 2048
#define KS 97      // int(2*(4*12+0.5)) = 97, odd
#define KH 48
#define KPAD 112   // taps zero-padded to multiple of 16; g[97..111] = 0
#define TR 8       // output rows per thread (R6: 8 -> 2x vblur waves, 32/CU)
#define NB_VB 2048 // vblur blocks: 2 ch x 256 strips x 4 colbands
#define NB_PK 4096 // pack blocks: HW/(256*4)
#define NB_TOT (NB_VB + NB_PK)

typedef float  nfloat4 __attribute__((ext_vector_type(4)));  // native vec (nontemporal ok)
typedef _Float16 h4v   __attribute__((ext_vector_type(4)));  // packed px: img.rgb + mask
typedef _Float16 h8v   __attribute__((ext_vector_type(8)));  // 2 packed px = 16B store

// ---------------------------------------------------------------------------
// wts layout: [0..111]=g0 (sigma0, zero-padded), [112..223]=g1, [224]=a0, [225]=a1
// ---------------------------------------------------------------------------
__global__ __launch_bounds__(128) void make_weights_k(const float* __restrict__ log_sigma,
                                                      const float* __restrict__ log_alpha,
                                                      float* __restrict__ wts) {
    __shared__ float e0s[KS], e1s[KS];
    __shared__ float sums[2];
    const int t = threadIdx.x;
    const float s0 = expf(log_sigma[0]);
    const float s1 = expf(log_sigma[1]);
    if (t < KS) {
        const float xx = (float)(t - KH);
        e0s[t] = expf(-(xx * xx) / (2.f * s0 * s0));
        e1s[t] = expf(-(xx * xx) / (2.f * s1 * s1));
    }
    __syncthreads();
    if (t == 0) {
        float a = 0.f, b = 0.f;
        for (int k = 0; k < KS; ++k) { a += e0s[k]; b += e1s[k]; }
        sums[0] = a; sums[1] = b;
    }
    __syncthreads();
    if (t < KPAD) {
        wts[t]        = (t < KS) ? e0s[t] / sums[0] : 0.f;
        wts[KPAD + t] = (t < KS) ? e1s[t] / sums[1] : 0.f;
    }
    if (t == 0) {
        wts[2 * KPAD]     = expf(log_alpha[0]);
        wts[2 * KPAD + 1] = expf(log_alpha[1]);
    }
}

// ---------------------------------------------------------------------------
// Vertical blur, R6: TR=8 for 2x wave parallelism (32 vblur waves/CU).
// History: R0/R3/R4 all ~69us at 16 vblur waves/CU, VALUBusy 17% -- per tap
// a wave issues 1 distance-0 load (~200cy L2 stall) covered by only 3
// same-SIMD partners x 64cy FMA => ~26% duty. Compiler provably refuses to
// hold a register prefetch ring (R1 spilled, R3 sank loads, R4 SGB ignored;
// VGPR always 64). R5 proved pack-wave partners do NOT speed vblur waves.
// So: more VBLUR waves. TR=8 doubles vblur waves; 7 partners x 32cy cover
// each 200cy stall. R2's TR=8 failure was confounded by fmaf-at-load gluing
// the waitcnt to each load (fixed since R3: loads are RAW d, linearity
// blur_pad0(2d-1) = 2*blur_pad0.5(d)-1 folded into hblur's alpha epilogue).
// Extra halo re-reads (13 vs 7 rows/output) are L3-absorbed (R2: FETCH
// unchanged) and only cost L2 BW (~10 of 34 TB/s).
// VGPR must stay <=64 for 8 waves/SIMD -> launch_bounds(256,8).
// Ascending-k order kept -> numerics bit-identical (absmax unchanged).
// ---------------------------------------------------------------------------
__device__ __forceinline__ void vblur_body_fast(const float* __restrict__ src,
                                                const float* __restrict__ g,
                                                float* __restrict__ dst,
                                                int col, int i0) {
    const float* __restrict__ p = src + (size_t)(i0 - KH) * W + col;  // row base+0
    float2 win[16];
    float2 acc[TR];
#pragma unroll
    for (int t = 0; t < TR; ++t) acc[t] = make_float2(0.f, 0.f);
    // prologue: rows base+0..15 -> win[0..15]
#pragma unroll
    for (int j = 0; j < 16; ++j) win[j] = *(const float2*)(p + (size_t)j * W);

    const float* __restrict__ q = p + (size_t)16 * W;   // first refill row (base+16)

    // taps 0..79: 5 dynamic groups of 16; refill row base+k+16 (rows 16..95)
    for (int m = 0; m < 5; ++m) {
#pragma unroll
        for (int r = 0; r < 16; ++r) {          // static ring indices
            const float2 nv = *(const float2*)(q + (size_t)r * W);
            const float gk = g[m * 16 + r];     // uniform -> s_load
#pragma unroll
            for (int t = 0; t < TR; ++t) {
                const float2 u = win[(r + t) & 15];
                acc[t].x = fmaf(gk, u.x, acc[t].x);
                acc[t].y = fmaf(gk, u.y, acc[t].y);
            }
            win[r] = nv;
        }
        q += (size_t)16 * W;
    }
    // taps 80..95 (peeled): refill rows 96..103 only at r <= 7 (static)
    {
#pragma unroll
        for (int r = 0; r < 16; ++r) {
            float2 nv;
            if (r <= 7)
                nv = *(const float2*)(q + (size_t)r * W);
            const float gk = g[80 + r];
#pragma unroll
            for (int t = 0; t < TR; ++t) {
                const float2 u = win[(r + t) & 15];
                acc[t].x = fmaf(gk, u.x, acc[t].x);
                acc[t].y = fmaf(gk, u.y, acc[t].y);
            }
            if (r <= 7)
                win[r] = nv;
        }
    }
    // tap 96: rows base+96..103 live in slots (96+t)&15 = t
    {
        const float gk = g[96];
#pragma unroll
        for (int t = 0; t < TR; ++t) {
            acc[t].x = fmaf(gk, win[t].x, acc[t].x);
            acc[t].y = fmaf(gk, win[t].y, acc[t].y);
        }
    }
#pragma unroll
    for (int t = 0; t < TR; ++t)
        *(float2*)(dst + (size_t)(i0 + t) * W + col) = acc[t];
}

// Guarded boundary variant (12/256 strips per channel-colband).
__device__ __forceinline__ float2 vload_row_g(const float* __restrict__ src, int row, int col) {
    float2 v = make_float2(0.5f, 0.5f);       // 0.5-pad == zero-pad of (2d-1)
    if ((unsigned)row < (unsigned)H)
        v = *(const float2*)(src + (size_t)row * W + col);
    return v;
}

__device__ __forceinline__ void vblur_body_guard(const float* __restrict__ src,
                                                 const float* __restrict__ g,
                                                 float* __restrict__ dst,
                                                 int col, int i0) {
    const int base = i0 - KH;
    float2 win[16];
    float2 acc[TR];
#pragma unroll
    for (int t = 0; t < TR; ++t) acc[t] = make_float2(0.f, 0.f);
#pragma unroll
    for (int j = 0; j < 16; ++j) win[j] = vload_row_g(src, base + j, col);

    for (int m = 0; m < 5; ++m) {
        const int kb = m * 16;
#pragma unroll
        for (int r = 0; r < 16; ++r) {
            const float gk = g[kb + r];
#pragma unroll
            for (int t = 0; t < TR; ++t) {
                const float2 u = win[(r + t) & 15];
                acc[t].x = fmaf(gk, u.x, acc[t].x);
                acc[t].y = fmaf(gk, u.y, acc[t].y);
            }
            win[r] = vload_row_g(src, base + kb + r + 16, col);
        }
    }
    {
#pragma unroll
        for (int r = 0; r < 16; ++r) {
            const float gk = g[80 + r];
#pragma unroll
            for (int t = 0; t < TR; ++t) {
                const float2 u = win[(r + t) & 15];
                acc[t].x = fmaf(gk, u.x, acc[t].x);
                acc[t].y = fmaf(gk, u.y, acc[t].y);
            }
            if (r <= 7)
                win[r] = vload_row_g(src, base + 96 + r, col);
        }
    }
    {
        const float gk = g[96];
#pragma unroll
        for (int t = 0; t < TR; ++t) {
            acc[t].x = fmaf(gk, win[t].x, acc[t].x);
            acc[t].y = fmaf(gk, win[t].y, acc[t].y);
        }
    }
#pragma unroll
    for (int t = 0; t < TR; ++t)
        *(float2*)(dst + (size_t)(i0 + t) * W + col) = acc[t];
}

// ---------------------------------------------------------------------------
// Fused kernel R6: 6144 blocks x 256 threads, IDs interleaved so pack blocks
// backfill retiring slots throughout (bid%3==0 -> vblur, else pack).
//   vblur: 2048 blocks = 2 ch x 256 row-strips (TR=8) x 4 colbands,
//          XCD y-band swizzle (XCD k owns rows [256k,256k+256)).
//   pack:  4096 blocks, 4 px/thread, image+mask -> f16 h4v.
// launch_bounds(256,8): forces VGPR<=64 so 8 waves/SIMD are possible.
// tmp holds blur(raw d) with 0.5-padding; 2x-1 folded into hblur epilogue.
// ---------------------------------------------------------------------------
__global__ __launch_bounds__(256, 8) void pv_k(const float* __restrict__ drand,
                                               const float* __restrict__ wts,
                                               const float* __restrict__ image,
                                               const float* __restrict__ mask,
                                               float* __restrict__ tmp,
                                               h4v* __restrict__ packed) {
    const size_t HW = (size_t)H * W;
    const int bid = blockIdx.x;
    const int tid = threadIdx.x;
    const bool do_vb = (bid % 3 == 0) || !packed;
    if (do_vb) {
        // --- vertical blur ---
        const int vb  = packed ? (bid / 3) : bid;   // 0..2047
        const int c   = vb >> 10;          // 1024 blocks per channel
        const int id  = vb & 1023;
        const int xcd = id & 7;            // XCD-band swizzle
        const int seq = id >> 3;           // 0..127
        const int strip = xcd * 32 + (seq >> 2);    // 0..255
        const int xb  = seq & 3;
        const int col = (xb * 256 + tid) * 2;
        const int i0  = strip * TR;
        const float* __restrict__ src = drand + (size_t)c * HW;
        const float* __restrict__ g   = wts + c * KPAD;
        float* __restrict__ dst       = tmp + (size_t)c * HW;
        // rows touched: [i0-48, i0+55]
        if (i0 >= KH && i0 + 55 <= H - 1)
            vblur_body_fast(src, g, dst, col, i0);
        else
            vblur_body_guard(src, g, dst, col, i0);
    } else {
        // --- pack: 4 px/thread, loads dwordx4, stores 2x16B ---
        const int pk = bid - bid / 3 - 1;           // 0..4095
        const size_t idx4 = ((size_t)pk * 256 + tid) * 4;
        const float4 p0 = *(const float4*)(image + idx4);
        const float4 p1 = *(const float4*)(image + HW + idx4);
        const float4 p2 = *(const float4*)(image + 2 * HW + idx4);
        const float4 pm = *(const float4*)(mask + idx4);
        h8v lo, hi;
        lo[0] = (_Float16)p0.x; lo[1] = (_Float16)p1.x; lo[2] = (_Float16)p2.x; lo[3] = (_Float16)pm.x;
        lo[4] = (_Float16)p0.y; lo[5] = (_Float16)p1.y; lo[6] = (_Float16)p2.y; lo[7] = (_Float16)pm.y;
        hi[0] = (_Float16)p0.z; hi[1] = (_Float16)p1.z; hi[2] = (_Float16)p2.z; hi[3] = (_Float16)pm.z;
        hi[4] = (_Float16)p0.w; hi[5] = (_Float16)p1.w; hi[6] = (_Float16)p2.w; hi[7] = (_Float16)pm.w;
        *(h8v*)(packed + idx4)     = lo;
        *(h8v*)(packed + idx4 + 2) = hi;
    }
}

// ---------------------------------------------------------------------------
// Kernel 2: one block per row (512 thr x 4 px), XCD row-band swizzle.
// Horizontal 97-tap blur of tmp -> (dy,dx). tmp is the RAW-field blur with
// 0.5 padding; the reference's 2x-1 transform is folded into the alpha
// scale: dyc = 2*a0*dy - a0. Bilinear gather from f16 packed buffer,
// nontemporal f32 out.
// Reference quirk: x-coordinate += dy (channel 0), y-coordinate += dx.
// UNCHANGED (isolating the pv_k change).
// ---------------------------------------------------------------------------
#define SW 2160     // LDS span: need idx <= 2155; mult of 4
template <bool PACKED>
__global__ __launch_bounds__(512) void hblur_sample_k(const float* __restrict__ tmp,
                                                      const float* __restrict__ wts,
                                                      const float* __restrict__ image,
                                                      const float* __restrict__ mask,
                                                      const h4v* __restrict__ packed,
                                                      float* __restrict__ out) {
    // XCD band swizzle: XCD k walks rows [256k, 256k+256) in order, so the
    // gather window stays in that XCD's L2.
    const int i   = (blockIdx.x & 7) * 256 + (blockIdx.x >> 3);
    const int tid = threadIdx.x;

    __shared__ __align__(16) float s0[SW];
    __shared__ __align__(16) float s1[SW];
    __shared__ __align__(16) float g0s[KPAD];
    __shared__ __align__(16) float g1s[KPAD];

    if (tid < KPAD) { g0s[tid] = wts[tid]; g1s[tid] = wts[KPAD + tid]; }

    const float* __restrict__ t0 = tmp + (size_t)i * W;
    const float* __restrict__ t1 = tmp + (size_t)H * W + (size_t)i * W;
    for (int idx = tid; idx < SW / 4; idx += 512) {
        const int colb = idx * 4 - KH;        // 16B aligned; all-in or all-out
        float4 v0 = make_float4(0.5f, 0.5f, 0.5f, 0.5f);   // 0.5-pad (raw field)
        float4 v1 = v0;
        if (colb >= 0 && colb + 3 < W) {
            v0 = *(const float4*)(t0 + colb);
            v1 = *(const float4*)(t1 + colb);
        }
        *(float4*)(s0 + idx * 4) = v0;
        *(float4*)(s1 + idx * 4) = v1;
    }
    __syncthreads();

    const int lb = tid * 4;                   // first of 4 pixels

    float4 A0 = *(const float4*)(s0 + lb), B0 = *(const float4*)(s0 + lb + 4);
    float4 A1 = *(const float4*)(s1 + lb), B1 = *(const float4*)(s1 + lb + 4);
    float dy[4] = {0.f, 0.f, 0.f, 0.f}, dx[4] = {0.f, 0.f, 0.f, 0.f};

#pragma unroll
    for (int kg = 0; kg < 26; ++kg) {         // 26 groups of 4 taps (g[97..103]=0)
        const int k0 = kg * 4;
        const float4 g0q = *(const float4*)(g0s + k0);       // broadcast
        const float4 g1q = *(const float4*)(g1s + k0);
        const float4 N0  = *(const float4*)(s0 + lb + k0 + 8);
        const float4 N1  = *(const float4*)(s1 + lb + k0 + 8);
        const float e0[8] = {A0.x, A0.y, A0.z, A0.w, B0.x, B0.y, B0.z, B0.w};
        const float e1[8] = {A1.x, A1.y, A1.z, A1.w, B1.x, B1.y, B1.z, B1.w};
#pragma unroll
        for (int j = 0; j < 4; ++j) {
            const float gj0 = j == 0 ? g0q.x : j == 1 ? g0q.y : j == 2 ? g0q.z : g0q.w;
            const float gj1 = j == 0 ? g1q.x : j == 1 ? g1q.y : j == 2 ? g1q.z : g1q.w;
#pragma unroll
            for (int c = 0; c < 4; ++c) {
                dy[c] = fmaf(gj0, e0[c + j], dy[c]);
                dx[c] = fmaf(gj1, e1[c + j], dx[c]);
            }
        }
        A0 = B0; B0 = N0; A1 = B1; B1 = N1;
    }

    const float a0 = wts[2 * KPAD];
    const float a1 = wts[2 * KPAD + 1];
    const float a0x2 = a0 + a0;
    const float a1x2 = a1 + a1;
    const float step = 2.f / 2047.f;
    float res[4][4];
#pragma unroll
    for (int c = 0; c < 4; ++c) {
        const int j = lb + c;
        const float dyc = fmaf(dy[c], a0x2, -a0);  // (2*hv(d)-1)*a0, folded 2x-1
        const float dxc = fmaf(dx[c], a1x2, -a1);
        float xn = -1.f + (float)j * step + dyc;   // gx + dy  (reference quirk)
        float yn = -1.f + (float)i * step + dxc;   // gy + dx
        xn = fminf(fmaxf(xn, -1.f), 1.f);
        yn = fminf(fmaxf(yn, -1.f), 1.f);

        const float x = (xn + 1.f) * 0.5f * (float)(W - 1);
        const float y = (yn + 1.f) * 0.5f * (float)(H - 1);
        const float x0f = floorf(x), y0f = floorf(y);
        const float wx = x - x0f, wy = y - y0f;

        int x0 = (int)x0f, y0 = (int)y0f;
        int x1 = x0 + 1, y1 = y0 + 1;
        x0 = min(max(x0, 0), W - 1); x1 = min(max(x1, 0), W - 1);
        y0 = min(max(y0, 0), H - 1); y1 = min(max(y1, 0), H - 1);

        const float w00 = (1.f - wx) * (1.f - wy);
        const float w10 = wx * (1.f - wy);
        const float w01 = (1.f - wx) * wy;
        const float w11 = wx * wy;

        const size_t i00 = (size_t)y0 * W + x0;
        const size_t i10 = (size_t)y0 * W + x1;
        const size_t i01 = (size_t)y1 * W + x0;
        const size_t i11 = (size_t)y1 * W + x1;

        if (PACKED) {
            const h4v v00 = packed[i00], v10 = packed[i10];
            const h4v v01 = packed[i01], v11 = packed[i11];
            res[0][c] = (float)v00[0] * w00 + (float)v10[0] * w10 + (float)v01[0] * w01 + (float)v11[0] * w11;
            res[1][c] = (float)v00[1] * w00 + (float)v10[1] * w10 + (float)v01[1] * w01 + (float)v11[1] * w11;
            res[2][c] = (float)v00[2] * w00 + (float)v10[2] * w10 + (float)v01[2] * w01 + (float)v11[2] * w11;
            res[3][c] = (float)v00[3] * w00 + (float)v10[3] * w10 + (float)v01[3] * w01 + (float)v11[3] * w11;
        } else {
#pragma unroll
            for (int p = 0; p < 3; ++p) {
                const float* __restrict__ pl = image + (size_t)p * H * W;
                res[p][c] = pl[i00] * w00 + pl[i10] * w10 + pl[i01] * w01 + pl[i11] * w11;
            }
            res[3][c] = mask[i00] * w00 + mask[i10] * w10 + mask[i01] * w01 + mask[i11] * w11;
        }
    }

    const size_t o = (size_t)i * W + lb;
#pragma unroll
    for (int p = 0; p < 4; ++p) {
        nfloat4 v;
        v.x = res[p][0]; v.y = res[p][1]; v.z = res[p][2]; v.w = res[p][3];
        __builtin_nontemporal_store(v, (nfloat4*)(out + (size_t)p * H * W + o));
    }
}

// ---------------------------------------------------------------------------
extern "C" void kernel_launch(void* const* d_in, const int* in_sizes, int n_in,
                              void* d_out, int out_size, void* d_ws, size_t ws_size,
                              hipStream_t stream) {
    const float* image     = (const float*)d_in[0];  // (3,2048,2048)
    const float* mask      = (const float*)d_in[1];  // (1,2048,2048)
    const float* drand     = (const float*)d_in[2];  // (1,2,2048,2048)
    const float* log_sigma = (const float*)d_in[3];  // (2,)
    const float* log_alpha = (const float*)d_in[4];  // (2,)
    float* out = (float*)d_out;                      // 3*HW img ++ 1*HW mask

    const size_t HW = (size_t)H * W;
    // packed f16 (HW * 8 B) + tmp (2*HW * 4 B) + wts (256 floats)
    const bool can_pack = ws_size >= HW * 8 + 2 * HW * 4 + 1024;

    h4v* packed; float* tmp; float* wts;
    if (can_pack) {
        packed = (h4v*)d_ws;                      // 32 MB, 16B aligned
        tmp    = (float*)((char*)d_ws + HW * 8);  // 32 MB
        wts    = tmp + 2 * HW;                    // 226 floats
    } else {
        packed = nullptr;
        tmp    = (float*)d_ws;
        wts    = tmp + 2 * HW;
    }

    make_weights_k<<<1, 128, 0, stream>>>(log_sigma, log_alpha, wts);
    pv_k<<<can_pack ? NB_TOT : NB_VB, 256, 0, stream>>>(drand, wts, image, mask,
                                                        tmp, packed);
    if (can_pack)
        hblur_sample_k<true><<<H, 512, 0, stream>>>(tmp, wts, image, mask, packed, out);
    else
        hblur_sample_k<false><<<H, 512, 0, stream>>>(tmp, wts, image, mask, packed, out);
}

// Round 7
// 242.584 us; speedup vs baseline: 1.3111x; 1.3111x over previous
//
#include <hip/hip_runtime.h>

#define H 2048
#define W 2048
#define KS 97      // int(2*(4*12+0.5)) = 97, odd
#define KH 48
#define KPAD 112   // taps zero-padded to multiple of 16; g[97..111] = 0
#define TR 8       // output rows per thread: 2048 vblur blocks -> 32 waves/CU
#define NB_VB 2048 // vblur blocks: 2 ch x 256 strips x 4 colbands
#define NB_PK 4096 // pack blocks: HW/(256*4)
#define NB_TOT (NB_VB + NB_PK)

typedef float  nfloat4 __attribute__((ext_vector_type(4)));  // native vec (nontemporal ok)
typedef _Float16 h4v   __attribute__((ext_vector_type(4)));  // packed px: img.rgb + mask
typedef _Float16 h8v   __attribute__((ext_vector_type(8)));  // 2 packed px = 16B store

// ---------------------------------------------------------------------------
// wts layout: [0..111]=g0 (sigma0, zero-padded), [112..223]=g1, [224]=a0, [225]=a1
// ---------------------------------------------------------------------------
__global__ __launch_bounds__(128) void make_weights_k(const float* __restrict__ log_sigma,
                                                      const float* __restrict__ log_alpha,
                                                      float* __restrict__ wts) {
    __shared__ float e0s[KS], e1s[KS];
    __shared__ float sums[2];
    const int t = threadIdx.x;
    const float s0 = expf(log_sigma[0]);
    const float s1 = expf(log_sigma[1]);
    if (t < KS) {
        const float xx = (float)(t - KH);
        e0s[t] = expf(-(xx * xx) / (2.f * s0 * s0));
        e1s[t] = expf(-(xx * xx) / (2.f * s1 * s1));
    }
    __syncthreads();
    if (t == 0) {
        float a = 0.f, b = 0.f;
        for (int k = 0; k < KS; ++k) { a += e0s[k]; b += e1s[k]; }
        sums[0] = a; sums[1] = b;
    }
    __syncthreads();
    if (t < KPAD) {
        wts[t]        = (t < KS) ? e0s[t] / sums[0] : 0.f;
        wts[KPAD + t] = (t < KS) ? e1s[t] / sums[1] : 0.f;
    }
    if (t == 0) {
        wts[2 * KPAD]     = expf(log_alpha[0]);
        wts[2 * KPAD + 1] = expf(log_alpha[1]);
    }
}

// ---------------------------------------------------------------------------
// Vertical blur, R7: TR=8 waves (32 vblur waves/CU) WITHOUT the register cap.
// R6 post-mortem: occupancy ~50% confirmed the TR=8 grid doubles resident
// waves, but __launch_bounds__(256,8) made the compiler allocate 32 VGPR ->
// the 16-slot ring spilled to scratch (WRITE_SIZE 228MB vs 66MB expected,
// FETCH +60MB) and time tripled. R7 keeps the TR=8 mapping and restores
// (256,4): compiler lands at its preferred ~64 VGPR (spill-free in every
// prior (256,4) round), and since 64 <= 512/8 the HARDWARE still admits
// 8 waves/SIMD -- occupancy comes from the 2048-block grid, not the bound.
// Dispatch order: vblur blocks FIRST (fill every CU with 8 vblur blocks =
// 32 waves from t=0), pack blocks after (backfill as vblur retires).
// Loads are RAW d (linearity: blur_pad0(2d-1) = 2*blur_pad0.5(d)-1, the
// 2x-1 is folded into hblur's alpha epilogue) -> pure loads, no glued VALU.
// Ascending-k order kept -> numerics bit-identical (absmax unchanged).
// ---------------------------------------------------------------------------
__device__ __forceinline__ void vblur_body_fast(const float* __restrict__ src,
                                                const float* __restrict__ g,
                                                float* __restrict__ dst,
                                                int col, int i0) {
    const float* __restrict__ p = src + (size_t)(i0 - KH) * W + col;  // row base+0
    float2 win[16];
    float2 acc[TR];
#pragma unroll
    for (int t = 0; t < TR; ++t) acc[t] = make_float2(0.f, 0.f);
    // prologue: rows base+0..15 -> win[0..15]
#pragma unroll
    for (int j = 0; j < 16; ++j) win[j] = *(const float2*)(p + (size_t)j * W);

    const float* __restrict__ q = p + (size_t)16 * W;   // first refill row (base+16)

    // taps 0..79: 5 dynamic groups of 16; refill row base+k+16 (rows 16..95)
    for (int m = 0; m < 5; ++m) {
#pragma unroll
        for (int r = 0; r < 16; ++r) {          // static ring indices
            const float2 nv = *(const float2*)(q + (size_t)r * W);
            const float gk = g[m * 16 + r];     // uniform -> s_load
#pragma unroll
            for (int t = 0; t < TR; ++t) {
                const float2 u = win[(r + t) & 15];
                acc[t].x = fmaf(gk, u.x, acc[t].x);
                acc[t].y = fmaf(gk, u.y, acc[t].y);
            }
            win[r] = nv;
        }
        q += (size_t)16 * W;
    }
    // taps 80..95 (peeled): refill rows 96..103 only at r <= 7 (static)
    {
#pragma unroll
        for (int r = 0; r < 16; ++r) {
            float2 nv;
            if (r <= 7)
                nv = *(const float2*)(q + (size_t)r * W);
            const float gk = g[80 + r];
#pragma unroll
            for (int t = 0; t < TR; ++t) {
                const float2 u = win[(r + t) & 15];
                acc[t].x = fmaf(gk, u.x, acc[t].x);
                acc[t].y = fmaf(gk, u.y, acc[t].y);
            }
            if (r <= 7)
                win[r] = nv;
        }
    }
    // tap 96: rows base+96..103 live in slots (96+t)&15 = t
    {
        const float gk = g[96];
#pragma unroll
        for (int t = 0; t < TR; ++t) {
            acc[t].x = fmaf(gk, win[t].x, acc[t].x);
            acc[t].y = fmaf(gk, win[t].y, acc[t].y);
        }
    }
#pragma unroll
    for (int t = 0; t < TR; ++t)
        *(float2*)(dst + (size_t)(i0 + t) * W + col) = acc[t];
}

// Guarded boundary variant (12/256 strips per channel-colband).
__device__ __forceinline__ float2 vload_row_g(const float* __restrict__ src, int row, int col) {
    float2 v = make_float2(0.5f, 0.5f);       // 0.5-pad == zero-pad of (2d-1)
    if ((unsigned)row < (unsigned)H)
        v = *(const float2*)(src + (size_t)row * W + col);
    return v;
}

__device__ __forceinline__ void vblur_body_guard(const float* __restrict__ src,
                                                 const float* __restrict__ g,
                                                 float* __restrict__ dst,
                                                 int col, int i0) {
    const int base = i0 - KH;
    float2 win[16];
    float2 acc[TR];
#pragma unroll
    for (int t = 0; t < TR; ++t) acc[t] = make_float2(0.f, 0.f);
#pragma unroll
    for (int j = 0; j < 16; ++j) win[j] = vload_row_g(src, base + j, col);

    for (int m = 0; m < 5; ++m) {
        const int kb = m * 16;
#pragma unroll
        for (int r = 0; r < 16; ++r) {
            const float gk = g[kb + r];
#pragma unroll
            for (int t = 0; t < TR; ++t) {
                const float2 u = win[(r + t) & 15];
                acc[t].x = fmaf(gk, u.x, acc[t].x);
                acc[t].y = fmaf(gk, u.y, acc[t].y);
            }
            win[r] = vload_row_g(src, base + kb + r + 16, col);
        }
    }
    {
#pragma unroll
        for (int r = 0; r < 16; ++r) {
            const float gk = g[80 + r];
#pragma unroll
            for (int t = 0; t < TR; ++t) {
                const float2 u = win[(r + t) & 15];
                acc[t].x = fmaf(gk, u.x, acc[t].x);
                acc[t].y = fmaf(gk, u.y, acc[t].y);
            }
            if (r <= 7)
                win[r] = vload_row_g(src, base + 96 + r, col);
        }
    }
    {
        const float gk = g[96];
#pragma unroll
        for (int t = 0; t < TR; ++t) {
            acc[t].x = fmaf(gk, win[t].x, acc[t].x);
            acc[t].y = fmaf(gk, win[t].y, acc[t].y);
        }
    }
#pragma unroll
    for (int t = 0; t < TR; ++t)
        *(float2*)(dst + (size_t)(i0 + t) * W + col) = acc[t];
}

// ---------------------------------------------------------------------------
// Fused kernel R7: blocks [0,2048) vblur (TR=8, XCD y-band swizzle),
// blocks [2048,6144) pack image+mask -> f16 h4v (4 px/thread).
// launch_bounds(256,4): proven spill-free (VGPR=64); HW occupancy of 8
// waves/SIMD still reachable since 64 <= 512/8.
// ---------------------------------------------------------------------------
__global__ __launch_bounds__(256, 4) void pv_k(const float* __restrict__ drand,
                                               const float* __restrict__ wts,
                                               const float* __restrict__ image,
                                               const float* __restrict__ mask,
                                               float* __restrict__ tmp,
                                               h4v* __restrict__ packed) {
    const size_t HW = (size_t)H * W;
    const int bid = blockIdx.x;
    const int tid = threadIdx.x;
    if (bid < NB_VB) {
        // --- vertical blur ---
        const int c   = bid >> 10;         // 1024 blocks per channel
        const int id  = bid & 1023;
        const int xcd = id & 7;            // XCD-band swizzle
        const int seq = id >> 3;           // 0..127
        const int strip = xcd * 32 + (seq >> 2);    // 0..255
        const int xb  = seq & 3;
        const int col = (xb * 256 + tid) * 2;
        const int i0  = strip * TR;
        const float* __restrict__ src = drand + (size_t)c * HW;
        const float* __restrict__ g   = wts + c * KPAD;
        float* __restrict__ dst       = tmp + (size_t)c * HW;
        // rows touched: [i0-48, i0+55]
        if (i0 >= KH && i0 + 55 <= H - 1)
            vblur_body_fast(src, g, dst, col, i0);
        else
            vblur_body_guard(src, g, dst, col, i0);
    } else {
        // --- pack: 4 px/thread, loads dwordx4, stores 2x16B ---
        const int pk = bid - NB_VB;                 // 0..4095
        const size_t idx4 = ((size_t)pk * 256 + tid) * 4;
        const float4 p0 = *(const float4*)(image + idx4);
        const float4 p1 = *(const float4*)(image + HW + idx4);
        const float4 p2 = *(const float4*)(image + 2 * HW + idx4);
        const float4 pm = *(const float4*)(mask + idx4);
        h8v lo, hi;
        lo[0] = (_Float16)p0.x; lo[1] = (_Float16)p1.x; lo[2] = (_Float16)p2.x; lo[3] = (_Float16)pm.x;
        lo[4] = (_Float16)p0.y; lo[5] = (_Float16)p1.y; lo[6] = (_Float16)p2.y; lo[7] = (_Float16)pm.y;
        hi[0] = (_Float16)p0.z; hi[1] = (_Float16)p1.z; hi[2] = (_Float16)p2.z; hi[3] = (_Float16)pm.z;
        hi[4] = (_Float16)p0.w; hi[5] = (_Float16)p1.w; hi[6] = (_Float16)p2.w; hi[7] = (_Float16)pm.w;
        *(h8v*)(packed + idx4)     = lo;
        *(h8v*)(packed + idx4 + 2) = hi;
    }
}

// ---------------------------------------------------------------------------
// Kernel 2: one block per row (512 thr x 4 px), XCD row-band swizzle.
// Horizontal 97-tap blur of tmp -> (dy,dx). tmp is the RAW-field blur with
// 0.5 padding; the reference's 2x-1 transform is folded into the alpha
// scale: dyc = 2*a0*dy - a0. Bilinear gather from f16 packed buffer,
// nontemporal f32 out.
// Reference quirk: x-coordinate += dy (channel 0), y-coordinate += dx.
// UNCHANGED (isolating the pv_k change).
// ---------------------------------------------------------------------------
#define SW 2160     // LDS span: need idx <= 2155; mult of 4
template <bool PACKED>
__global__ __launch_bounds__(512) void hblur_sample_k(const float* __restrict__ tmp,
                                                      const float* __restrict__ wts,
                                                      const float* __restrict__ image,
                                                      const float* __restrict__ mask,
                                                      const h4v* __restrict__ packed,
                                                      float* __restrict__ out) {
    // XCD band swizzle: XCD k walks rows [256k, 256k+256) in order, so the
    // gather window stays in that XCD's L2.
    const int i   = (blockIdx.x & 7) * 256 + (blockIdx.x >> 3);
    const int tid = threadIdx.x;

    __shared__ __align__(16) float s0[SW];
    __shared__ __align__(16) float s1[SW];
    __shared__ __align__(16) float g0s[KPAD];
    __shared__ __align__(16) float g1s[KPAD];

    if (tid < KPAD) { g0s[tid] = wts[tid]; g1s[tid] = wts[KPAD + tid]; }

    const float* __restrict__ t0 = tmp + (size_t)i * W;
    const float* __restrict__ t1 = tmp + (size_t)H * W + (size_t)i * W;
    for (int idx = tid; idx < SW / 4; idx += 512) {
        const int colb = idx * 4 - KH;        // 16B aligned; all-in or all-out
        float4 v0 = make_float4(0.5f, 0.5f, 0.5f, 0.5f);   // 0.5-pad (raw field)
        float4 v1 = v0;
        if (colb >= 0 && colb + 3 < W) {
            v0 = *(const float4*)(t0 + colb);
            v1 = *(const float4*)(t1 + colb);
        }
        *(float4*)(s0 + idx * 4) = v0;
        *(float4*)(s1 + idx * 4) = v1;
    }
    __syncthreads();

    const int lb = tid * 4;                   // first of 4 pixels

    float4 A0 = *(const float4*)(s0 + lb), B0 = *(const float4*)(s0 + lb + 4);
    float4 A1 = *(const float4*)(s1 + lb), B1 = *(const float4*)(s1 + lb + 4);
    float dy[4] = {0.f, 0.f, 0.f, 0.f}, dx[4] = {0.f, 0.f, 0.f, 0.f};

#pragma unroll
    for (int kg = 0; kg < 26; ++kg) {         // 26 groups of 4 taps (g[97..103]=0)
        const int k0 = kg * 4;
        const float4 g0q = *(const float4*)(g0s + k0);       // broadcast
        const float4 g1q = *(const float4*)(g1s + k0);
        const float4 N0  = *(const float4*)(s0 + lb + k0 + 8);
        const float4 N1  = *(const float4*)(s1 + lb + k0 + 8);
        const float e0[8] = {A0.x, A0.y, A0.z, A0.w, B0.x, B0.y, B0.z, B0.w};
        const float e1[8] = {A1.x, A1.y, A1.z, A1.w, B1.x, B1.y, B1.z, B1.w};
#pragma unroll
        for (int j = 0; j < 4; ++j) {
            const float gj0 = j == 0 ? g0q.x : j == 1 ? g0q.y : j == 2 ? g0q.z : g0q.w;
            const float gj1 = j == 0 ? g1q.x : j == 1 ? g1q.y : j == 2 ? g1q.z : g1q.w;
#pragma unroll
            for (int c = 0; c < 4; ++c) {
                dy[c] = fmaf(gj0, e0[c + j], dy[c]);
                dx[c] = fmaf(gj1, e1[c + j], dx[c]);
            }
        }
        A0 = B0; B0 = N0; A1 = B1; B1 = N1;
    }

    const float a0 = wts[2 * KPAD];
    const float a1 = wts[2 * KPAD + 1];
    const float a0x2 = a0 + a0;
    const float a1x2 = a1 + a1;
    const float step = 2.f / 2047.f;
    float res[4][4];
#pragma unroll
    for (int c = 0; c < 4; ++c) {
        const int j = lb + c;
        const float dyc = fmaf(dy[c], a0x2, -a0);  // (2*hv(d)-1)*a0, folded 2x-1
        const float dxc = fmaf(dx[c], a1x2, -a1);
        float xn = -1.f + (float)j * step + dyc;   // gx + dy  (reference quirk)
        float yn = -1.f + (float)i * step + dxc;   // gy + dx
        xn = fminf(fmaxf(xn, -1.f), 1.f);
        yn = fminf(fmaxf(yn, -1.f), 1.f);

        const float x = (xn + 1.f) * 0.5f * (float)(W - 1);
        const float y = (yn + 1.f) * 0.5f * (float)(H - 1);
        const float x0f = floorf(x), y0f = floorf(y);
        const float wx = x - x0f, wy = y - y0f;

        int x0 = (int)x0f, y0 = (int)y0f;
        int x1 = x0 + 1, y1 = y0 + 1;
        x0 = min(max(x0, 0), W - 1); x1 = min(max(x1, 0), W - 1);
        y0 = min(max(y0, 0), H - 1); y1 = min(max(y1, 0), H - 1);

        const float w00 = (1.f - wx) * (1.f - wy);
        const float w10 = wx * (1.f - wy);
        const float w01 = (1.f - wx) * wy;
        const float w11 = wx * wy;

        const size_t i00 = (size_t)y0 * W + x0;
        const size_t i10 = (size_t)y0 * W + x1;
        const size_t i01 = (size_t)y1 * W + x0;
        const size_t i11 = (size_t)y1 * W + x1;

        if (PACKED) {
            const h4v v00 = packed[i00], v10 = packed[i10];
            const h4v v01 = packed[i01], v11 = packed[i11];
            res[0][c] = (float)v00[0] * w00 + (float)v10[0] * w10 + (float)v01[0] * w01 + (float)v11[0] * w11;
            res[1][c] = (float)v00[1] * w00 + (float)v10[1] * w10 + (float)v01[1] * w01 + (float)v11[1] * w11;
            res[2][c] = (float)v00[2] * w00 + (float)v10[2] * w10 + (float)v01[2] * w01 + (float)v11[2] * w11;
            res[3][c] = (float)v00[3] * w00 + (float)v10[3] * w10 + (float)v01[3] * w01 + (float)v11[3] * w11;
        } else {
#pragma unroll
            for (int p = 0; p < 3; ++p) {
                const float* __restrict__ pl = image + (size_t)p * H * W;
                res[p][c] = pl[i00] * w00 + pl[i10] * w10 + pl[i01] * w01 + pl[i11] * w11;
            }
            res[3][c] = mask[i00] * w00 + mask[i10] * w10 + mask[i01] * w01 + mask[i11] * w11;
        }
    }

    const size_t o = (size_t)i * W + lb;
#pragma unroll
    for (int p = 0; p < 4; ++p) {
        nfloat4 v;
        v.x = res[p][0]; v.y = res[p][1]; v.z = res[p][2]; v.w = res[p][3];
        __builtin_nontemporal_store(v, (nfloat4*)(out + (size_t)p * H * W + o));
    }
}

// ---------------------------------------------------------------------------
extern "C" void kernel_launch(void* const* d_in, const int* in_sizes, int n_in,
                              void* d_out, int out_size, void* d_ws, size_t ws_size,
                              hipStream_t stream) {
    const float* image     = (const float*)d_in[0];  // (3,2048,2048)
    const float* mask      = (const float*)d_in[1];  // (1,2048,2048)
    const float* drand     = (const float*)d_in[2];  // (1,2,2048,2048)
    const float* log_sigma = (const float*)d_in[3];  // (2,)
    const float* log_alpha = (const float*)d_in[4];  // (2,)
    float* out = (float*)d_out;                      // 3*HW img ++ 1*HW mask

    const size_t HW = (size_t)H * W;
    // packed f16 (HW * 8 B) + tmp (2*HW * 4 B) + wts (256 floats)
    const bool can_pack = ws_size >= HW * 8 + 2 * HW * 4 + 1024;

    h4v* packed; float* tmp; float* wts;
    if (can_pack) {
        packed = (h4v*)d_ws;                      // 32 MB, 16B aligned
        tmp    = (float*)((char*)d_ws + HW * 8);  // 32 MB
        wts    = tmp + 2 * HW;                    // 226 floats
    } else {
        packed = nullptr;
        tmp    = (float*)d_ws;
        wts    = tmp + 2 * HW;
    }

    make_weights_k<<<1, 128, 0, stream>>>(log_sigma, log_alpha, wts);
    pv_k<<<can_pack ? NB_TOT : NB_VB, 256, 0, stream>>>(drand, wts, image, mask,
                                                        tmp, packed);
    if (can_pack)
        hblur_sample_k<true><<<H, 512, 0, stream>>>(tmp, wts, image, mask, packed, out);
    else
        hblur_sample_k<false><<<H, 512, 0, stream>>>(tmp, wts, image, mask, packed, out);
}

// Round 8
// 241.658 us; speedup vs baseline: 1.3162x; 1.0038x over previous
//
#include <hip/hip_runtime.h>

#define H 2048
#define W 2048
#define KS 97      // int(2*(4*12+0.5)) = 97, odd
#define KH 48
#define KPAD 112   // taps zero-padded to multiple of 16; g[97..111] = 0
#define TR 16      // output rows per thread, vertical pass (R4-best, frozen)
#define RING 24    // ring slots (R4 layout; compiler collapses, harmless)
#define NB_VB 1024 // vblur blocks: (2048/512) x (2048/16) x 2
#define NB_PK 4096 // pack blocks: HW/(256*4)

typedef float  nfloat4 __attribute__((ext_vector_type(4)));  // native vec (nontemporal ok)
typedef _Float16 h4v   __attribute__((ext_vector_type(4)));  // packed px: img.rgb + mask
typedef _Float16 h8v   __attribute__((ext_vector_type(8)));  // 2 packed px = 16B store

// sched_group_barrier masks (LLVM SchedGroupMask) -- kept from R4 (neutral)
#define SGB __builtin_amdgcn_sched_group_barrier
#define SG_VALU      0x2
#define SG_VMEM_READ 0x20

// ---------------------------------------------------------------------------
// wts layout: [0..111]=g0 (sigma0, zero-padded), [112..223]=g1, [224]=a0, [225]=a1
// ---------------------------------------------------------------------------
__global__ __launch_bounds__(128) void make_weights_k(const float* __restrict__ log_sigma,
                                                      const float* __restrict__ log_alpha,
                                                      float* __restrict__ wts) {
    __shared__ float e0s[KS], e1s[KS];
    __shared__ float sums[2];
    const int t = threadIdx.x;
    const float s0 = expf(log_sigma[0]);
    const float s1 = expf(log_sigma[1]);
    if (t < KS) {
        const float xx = (float)(t - KH);
        e0s[t] = expf(-(xx * xx) / (2.f * s0 * s0));
        e1s[t] = expf(-(xx * xx) / (2.f * s1 * s1));
    }
    __syncthreads();
    if (t == 0) {
        float a = 0.f, b = 0.f;
        for (int k = 0; k < KS; ++k) { a += e0s[k]; b += e1s[k]; }
        sums[0] = a; sums[1] = b;
    }
    __syncthreads();
    if (t < KPAD) {
        wts[t]        = (t < KS) ? e0s[t] / sums[0] : 0.f;
        wts[KPAD + t] = (t < KS) ? e1s[t] / sums[1] : 0.f;
    }
    if (t == 0) {
        wts[2 * KPAD]     = expf(log_alpha[0]);
        wts[2 * KPAD + 1] = expf(log_alpha[1]);
    }
}

// ---------------------------------------------------------------------------
// Vertical blur: R4 configuration, FROZEN. R0/R3/R4 all land at ~69us; R5-R7
// proved neither wave-count (TR=8, occupancy capped ~16 waves/CU at VGPR=64),
// nor SGB scheduling, nor register rings move it -- this access pattern's
// latency floor. Loads are RAW d (linearity: blur_pad0(2d-1) =
// 2*blur_pad0.5(d)-1, the 2x-1 folded into hblur's alpha epilogue).
// ---------------------------------------------------------------------------
__device__ __forceinline__ void vblur_body_fast(const float* __restrict__ src,
                                                const float* __restrict__ g,
                                                float* __restrict__ dst,
                                                int col, int i0) {
    const float* __restrict__ p = src + (size_t)(i0 - KH) * W + col;  // row base+0
    float2 win[RING];
    float2 acc[TR];
#pragma unroll
    for (int t = 0; t < TR; ++t) acc[t] = make_float2(0.f, 0.f);
#pragma unroll
    for (int j = 0; j < RING; ++j) win[j] = *(const float2*)(p + (size_t)j * W);

    const float* __restrict__ q = p + (size_t)RING * W;   // first refill row (base+24)

    for (int m = 0; m < 3; ++m) {
#pragma unroll
        for (int r = 0; r < 24; ++r) {          // static ring indices
            const float2 nv = *(const float2*)(q + (size_t)r * W);
            SGB(SG_VMEM_READ, 1, 0);
            const float gk = g[m * 24 + r];     // uniform -> s_load
#pragma unroll
            for (int t = 0; t < TR; ++t) {
                const int w = (r + t) < 24 ? (r + t) : (r + t - 24);
                acc[t].x = fmaf(gk, win[w].x, acc[t].x);
                acc[t].y = fmaf(gk, win[w].y, acc[t].y);
            }
            SGB(SG_VALU, 36, 0);
            win[r] = nv;
        }
        q += (size_t)24 * W;
    }
    {
#pragma unroll
        for (int r = 0; r < 24; ++r) {          // taps 72..95
            float2 nv;
            if (r <= 15) {
                nv = *(const float2*)(q + (size_t)r * W);
                SGB(SG_VMEM_READ, 1, 0);
            }
            const float gk = g[72 + r];
#pragma unroll
            for (int t = 0; t < TR; ++t) {
                const int w = (r + t) < 24 ? (r + t) : (r + t - 24);
                acc[t].x = fmaf(gk, win[w].x, acc[t].x);
                acc[t].y = fmaf(gk, win[w].y, acc[t].y);
            }
            SGB(SG_VALU, 36, 0);
            if (r <= 15)
                win[r] = nv;
        }
    }
    {
        const float gk = g[96];
#pragma unroll
        for (int t = 0; t < TR; ++t) {
            acc[t].x = fmaf(gk, win[t].x, acc[t].x);
            acc[t].y = fmaf(gk, win[t].y, acc[t].y);
        }
    }
#pragma unroll
    for (int t = 0; t < TR; ++t)
        *(float2*)(dst + (size_t)(i0 + t) * W + col) = acc[t];
}

// Guarded boundary variant (6/128 strips per channel-colband).
__device__ __forceinline__ float2 vload_row_g(const float* __restrict__ src, int row, int col) {
    float2 v = make_float2(0.5f, 0.5f);       // 0.5-pad == zero-pad of (2d-1)
    if ((unsigned)row < (unsigned)H)
        v = *(const float2*)(src + (size_t)row * W + col);
    return v;
}

__device__ __forceinline__ void vblur_body_guard(const float* __restrict__ src,
                                                 const float* __restrict__ g,
                                                 float* __restrict__ dst,
                                                 int col, int i0) {
    const int base = i0 - KH;
    float2 win[RING];
    float2 acc[TR];
#pragma unroll
    for (int t = 0; t < TR; ++t) acc[t] = make_float2(0.f, 0.f);
#pragma unroll
    for (int j = 0; j < RING; ++j) win[j] = vload_row_g(src, base + j, col);

    for (int m = 0; m < 3; ++m) {
        const int kb = m * 24;
#pragma unroll
        for (int r = 0; r < 24; ++r) {
            const float gk = g[kb + r];
#pragma unroll
            for (int t = 0; t < TR; ++t) {
                const int w = (r + t) < 24 ? (r + t) : (r + t - 24);
                acc[t].x = fmaf(gk, win[w].x, acc[t].x);
                acc[t].y = fmaf(gk, win[w].y, acc[t].y);
            }
            win[r] = vload_row_g(src, base + kb + r + 24, col);
        }
    }
    {
#pragma unroll
        for (int r = 0; r < 24; ++r) {
            const float gk = g[72 + r];
#pragma unroll
            for (int t = 0; t < TR; ++t) {
                const int w = (r + t) < 24 ? (r + t) : (r + t - 24);
                acc[t].x = fmaf(gk, win[w].x, acc[t].x);
                acc[t].y = fmaf(gk, win[w].y, acc[t].y);
            }
            if (r <= 15)
                win[r] = vload_row_g(src, base + 96 + r, col);
        }
    }
    {
        const float gk = g[96];
#pragma unroll
        for (int t = 0; t < TR; ++t) {
            acc[t].x = fmaf(gk, win[t].x, acc[t].x);
            acc[t].y = fmaf(gk, win[t].y, acc[t].y);
        }
    }
#pragma unroll
    for (int t = 0; t < TR; ++t)
        *(float2*)(dst + (size_t)(i0 + t) * W + col) = acc[t];
}

// ---------------------------------------------------------------------------
// Fused kernel (R4 exact): blocks [0,1024) vblur (XCD y-band swizzle),
// blocks [1024,5120) pack image+mask -> f16 h4v (4 px/thread).
// ---------------------------------------------------------------------------
__global__ __launch_bounds__(256, 4) void pv_k(const float* __restrict__ drand,
                                               const float* __restrict__ wts,
                                               const float* __restrict__ image,
                                               const float* __restrict__ mask,
                                               float* __restrict__ tmp,
                                               h4v* __restrict__ packed) {
    const size_t HW = (size_t)H * W;
    const int bid = blockIdx.x;
    if (bid < NB_VB) {
        const int c   = bid >> 9;          // 512 blocks per channel
        const int id  = bid & 511;
        const int xcd = id & 7;            // XCD-band swizzle
        const int seq = id >> 3;
        const int yb  = xcd * 16 + (seq >> 2);
        const int xb  = seq & 3;
        const int col = (xb * 256 + threadIdx.x) * 2;
        const int i0  = yb * TR;
        const float* __restrict__ src = drand + (size_t)c * HW;
        const float* __restrict__ g   = wts + c * KPAD;
        float* __restrict__ dst       = tmp + (size_t)c * HW;
        if (i0 >= KH && i0 + 63 <= H - 1)
            vblur_body_fast(src, g, dst, col, i0);
        else
            vblur_body_guard(src, g, dst, col, i0);
    } else {
        const size_t idx4 = ((size_t)(bid - NB_VB) * 256 + threadIdx.x) * 4;
        const float4 p0 = *(const float4*)(image + idx4);
        const float4 p1 = *(const float4*)(image + HW + idx4);
        const float4 p2 = *(const float4*)(image + 2 * HW + idx4);
        const float4 pm = *(const float4*)(mask + idx4);
        h8v lo, hi;
        lo[0] = (_Float16)p0.x; lo[1] = (_Float16)p1.x; lo[2] = (_Float16)p2.x; lo[3] = (_Float16)pm.x;
        lo[4] = (_Float16)p0.y; lo[5] = (_Float16)p1.y; lo[6] = (_Float16)p2.y; lo[7] = (_Float16)pm.y;
        hi[0] = (_Float16)p0.z; hi[1] = (_Float16)p1.z; hi[2] = (_Float16)p2.z; hi[3] = (_Float16)pm.z;
        hi[4] = (_Float16)p0.w; hi[5] = (_Float16)p1.w; hi[6] = (_Float16)p2.w; hi[7] = (_Float16)pm.w;
        *(h8v*)(packed + idx4)     = lo;
        *(h8v*)(packed + idx4 + 2) = hi;
    }
}

// ---------------------------------------------------------------------------
// Kernel 2, R8 rewrite: one block per row, 256 threads x 8 px (was 512x4).
// Why: hblur's inner loop issued ~108 ds_read_b128/thread -- 52 non-broadcast
// N-reads (LDS BW: ~1KiB/wave each) + 52 broadcast g-reads (issue + lgkm wait
// glued into the FMA stream). 8 px/thread halves LDS traffic per pixel (one
// N-read now feeds 8 px), and g moves to SCALAR loads from the uniform wts
// pointer (s_load_dwordx4, zero LDS, zero vector-issue). 256-thread blocks:
// ~56 VGPR in the tap loop -> up to 8 blocks/CU (LDS 17.3KB) = 32 waves/CU
// to hide the gather latency in the epilogue.
// tmp is the RAW-field blur with 0.5 padding; the reference's 2x-1 is folded
// into the alpha scale: dyc = 2*a0*dy - a0. Bilinear gather from f16 packed.
// Reference quirk: x-coordinate += dy (channel 0), y-coordinate += dx.
// ---------------------------------------------------------------------------
#define SW 2160     // LDS span: need idx <= 2155; mult of 4
template <bool PACKED>
__global__ __launch_bounds__(256) void hblur_sample_k(const float* __restrict__ tmp,
                                                      const float* __restrict__ wts,
                                                      const float* __restrict__ image,
                                                      const float* __restrict__ mask,
                                                      const h4v* __restrict__ packed,
                                                      float* __restrict__ out) {
    // XCD band swizzle: XCD k walks rows [256k, 256k+256) in order.
    const int i   = (blockIdx.x & 7) * 256 + (blockIdx.x >> 3);
    const int tid = threadIdx.x;

    __shared__ __align__(16) float s0[SW];
    __shared__ __align__(16) float s1[SW];

    const float* __restrict__ t0 = tmp + (size_t)i * W;
    const float* __restrict__ t1 = tmp + (size_t)H * W + (size_t)i * W;
    for (int idx = tid; idx < SW / 4; idx += 256) {
        const int colb = idx * 4 - KH;        // 16B aligned; all-in or all-out
        float4 v0 = make_float4(0.5f, 0.5f, 0.5f, 0.5f);   // 0.5-pad (raw field)
        float4 v1 = v0;
        if (colb >= 0 && colb + 3 < W) {
            v0 = *(const float4*)(t0 + colb);
            v1 = *(const float4*)(t1 + colb);
        }
        *(float4*)(s0 + idx * 4) = v0;
        *(float4*)(s1 + idx * 4) = v1;
    }
    __syncthreads();

    const int lb = tid * 8;                   // first of 8 pixels

    float4 A0 = *(const float4*)(s0 + lb);
    float4 B0 = *(const float4*)(s0 + lb + 4);
    float4 C0 = *(const float4*)(s0 + lb + 8);
    float4 A1 = *(const float4*)(s1 + lb);
    float4 B1 = *(const float4*)(s1 + lb + 4);
    float4 C1 = *(const float4*)(s1 + lb + 8);
    float dy[8] = {0.f, 0.f, 0.f, 0.f, 0.f, 0.f, 0.f, 0.f};
    float dx[8] = {0.f, 0.f, 0.f, 0.f, 0.f, 0.f, 0.f, 0.f};

#pragma unroll
    for (int kg = 0; kg < 26; ++kg) {         // 26 groups of 4 taps (g[97..103]=0)
        const int k0 = kg * 4;
        const float4 g0q = *(const float4*)(wts + k0);          // uniform -> s_load
        const float4 g1q = *(const float4*)(wts + KPAD + k0);   // uniform -> s_load
        const float4 N0  = *(const float4*)(s0 + lb + k0 + 12);
        const float4 N1  = *(const float4*)(s1 + lb + k0 + 12);
        const float e0[12] = {A0.x, A0.y, A0.z, A0.w, B0.x, B0.y, B0.z, B0.w,
                              C0.x, C0.y, C0.z, C0.w};
        const float e1[12] = {A1.x, A1.y, A1.z, A1.w, B1.x, B1.y, B1.z, B1.w,
                              C1.x, C1.y, C1.z, C1.w};
#pragma unroll
        for (int j = 0; j < 4; ++j) {
            const float gj0 = j == 0 ? g0q.x : j == 1 ? g0q.y : j == 2 ? g0q.z : g0q.w;
            const float gj1 = j == 0 ? g1q.x : j == 1 ? g1q.y : j == 2 ? g1q.z : g1q.w;
#pragma unroll
            for (int c = 0; c < 8; ++c) {
                dy[c] = fmaf(gj0, e0[c + j], dy[c]);
                dx[c] = fmaf(gj1, e1[c + j], dx[c]);
            }
        }
        A0 = B0; B0 = C0; C0 = N0;
        A1 = B1; B1 = C1; C1 = N1;
    }

    const float a0 = wts[2 * KPAD];
    const float a1 = wts[2 * KPAD + 1];
    const float a0x2 = a0 + a0;
    const float a1x2 = a1 + a1;
    const float step = 2.f / 2047.f;
    // epilogue in two 4-px halves (bounds res[][] live range / VGPR)
#pragma unroll
    for (int h = 0; h < 2; ++h) {
        float res[4][4];
#pragma unroll
        for (int c4 = 0; c4 < 4; ++c4) {
            const int c = h * 4 + c4;
            const int j = lb + c;
            const float dyc = fmaf(dy[c], a0x2, -a0);  // (2*hv(d)-1)*a0, folded 2x-1
            const float dxc = fmaf(dx[c], a1x2, -a1);
            float xn = -1.f + (float)j * step + dyc;   // gx + dy  (reference quirk)
            float yn = -1.f + (float)i * step + dxc;   // gy + dx
            xn = fminf(fmaxf(xn, -1.f), 1.f);
            yn = fminf(fmaxf(yn, -1.f), 1.f);

            const float x = (xn + 1.f) * 0.5f * (float)(W - 1);
            const float y = (yn + 1.f) * 0.5f * (float)(H - 1);
            const float x0f = floorf(x), y0f = floorf(y);
            const float wx = x - x0f, wy = y - y0f;

            int x0 = (int)x0f, y0 = (int)y0f;
            int x1 = x0 + 1, y1 = y0 + 1;
            x0 = min(max(x0, 0), W - 1); x1 = min(max(x1, 0), W - 1);
            y0 = min(max(y0, 0), H - 1); y1 = min(max(y1, 0), H - 1);

            const float w00 = (1.f - wx) * (1.f - wy);
            const float w10 = wx * (1.f - wy);
            const float w01 = (1.f - wx) * wy;
            const float w11 = wx * wy;

            const size_t i00 = (size_t)y0 * W + x0;
            const size_t i10 = (size_t)y0 * W + x1;
            const size_t i01 = (size_t)y1 * W + x0;
            const size_t i11 = (size_t)y1 * W + x1;

            if (PACKED) {
                const h4v v00 = packed[i00], v10 = packed[i10];
                const h4v v01 = packed[i01], v11 = packed[i11];
                res[0][c4] = (float)v00[0] * w00 + (float)v10[0] * w10 + (float)v01[0] * w01 + (float)v11[0] * w11;
                res[1][c4] = (float)v00[1] * w00 + (float)v10[1] * w10 + (float)v01[1] * w01 + (float)v11[1] * w11;
                res[2][c4] = (float)v00[2] * w00 + (float)v10[2] * w10 + (float)v01[2] * w01 + (float)v11[2] * w11;
                res[3][c4] = (float)v00[3] * w00 + (float)v10[3] * w10 + (float)v01[3] * w01 + (float)v11[3] * w11;
            } else {
#pragma unroll
                for (int p = 0; p < 3; ++p) {
                    const float* __restrict__ pl = image + (size_t)p * H * W;
                    res[p][c4] = pl[i00] * w00 + pl[i10] * w10 + pl[i01] * w01 + pl[i11] * w11;
                }
                res[3][c4] = mask[i00] * w00 + mask[i10] * w10 + mask[i01] * w01 + mask[i11] * w11;
            }
        }
        const size_t o = (size_t)i * W + lb + h * 4;
#pragma unroll
        for (int p = 0; p < 4; ++p) {
            nfloat4 v;
            v.x = res[p][0]; v.y = res[p][1]; v.z = res[p][2]; v.w = res[p][3];
            __builtin_nontemporal_store(v, (nfloat4*)(out + (size_t)p * H * W + o));
        }
    }
}

// ---------------------------------------------------------------------------
extern "C" void kernel_launch(void* const* d_in, const int* in_sizes, int n_in,
                              void* d_out, int out_size, void* d_ws, size_t ws_size,
                              hipStream_t stream) {
    const float* image     = (const float*)d_in[0];  // (3,2048,2048)
    const float* mask      = (const float*)d_in[1];  // (1,2048,2048)
    const float* drand     = (const float*)d_in[2];  // (1,2,2048,2048)
    const float* log_sigma = (const float*)d_in[3];  // (2,)
    const float* log_alpha = (const float*)d_in[4];  // (2,)
    float* out = (float*)d_out;                      // 3*HW img ++ 1*HW mask

    const size_t HW = (size_t)H * W;
    // packed f16 (HW * 8 B) + tmp (2*HW * 4 B) + wts (256 floats)
    const bool can_pack = ws_size >= HW * 8 + 2 * HW * 4 + 1024;

    h4v* packed; float* tmp; float* wts;
    if (can_pack) {
        packed = (h4v*)d_ws;                      // 32 MB, 16B aligned
        tmp    = (float*)((char*)d_ws + HW * 8);  // 32 MB
        wts    = tmp + 2 * HW;                    // 226 floats
    } else {
        packed = nullptr;
        tmp    = (float*)d_ws;
        wts    = tmp + 2 * HW;
    }

    make_weights_k<<<1, 128, 0, stream>>>(log_sigma, log_alpha, wts);
    pv_k<<<can_pack ? (NB_VB + NB_PK) : NB_VB, 256, 0, stream>>>(drand, wts, image, mask,
                                                                 tmp, packed);
    if (can_pack)
        hblur_sample_k<true><<<H, 256, 0, stream>>>(tmp, wts, image, mask, packed, out);
    else
        hblur_sample_k<false><<<H, 256, 0, stream>>>(tmp, wts, image, mask, packed, out);
}

// Round 9
// 225.765 us; speedup vs baseline: 1.4088x; 1.0704x over previous
//
#include <hip/hip_runtime.h>

#define H 2048
#define W 2048
#define KS 97      // int(2*(4*12+0.5)) = 97, odd
#define KH 48
#define KPAD 112   // taps zero-padded to multiple of 16; g[97..111] = 0
#define TR 16      // output rows per thread, vertical pass (R4-best, frozen)
#define RING 24    // ring slots (R4 layout; compiler collapses, harmless)
#define NB_VB 1024 // vblur blocks: (2048/512) x (2048/16) x 2
#define NB_PK 4096 // pack blocks: HW/(256*4)

typedef float  nfloat4 __attribute__((ext_vector_type(4)));  // native vec (nontemporal ok)
typedef _Float16 h4v   __attribute__((ext_vector_type(4)));  // packed px: img.rgb + mask
typedef _Float16 h8v   __attribute__((ext_vector_type(8)));  // 2 packed px = 16B store

// sched_group_barrier masks (LLVM SchedGroupMask) -- kept from R4 (neutral)
#define SGB __builtin_amdgcn_sched_group_barrier
#define SG_VALU      0x2
#define SG_VMEM_READ 0x20

// ---------------------------------------------------------------------------
// wts layout: [0..111]=g0 (sigma0, zero-padded), [112..223]=g1, [224]=a0, [225]=a1
// ---------------------------------------------------------------------------
__global__ __launch_bounds__(128) void make_weights_k(const float* __restrict__ log_sigma,
                                                      const float* __restrict__ log_alpha,
                                                      float* __restrict__ wts) {
    __shared__ float e0s[KS], e1s[KS];
    __shared__ float sums[2];
    const int t = threadIdx.x;
    const float s0 = expf(log_sigma[0]);
    const float s1 = expf(log_sigma[1]);
    if (t < KS) {
        const float xx = (float)(t - KH);
        e0s[t] = expf(-(xx * xx) / (2.f * s0 * s0));
        e1s[t] = expf(-(xx * xx) / (2.f * s1 * s1));
    }
    __syncthreads();
    if (t == 0) {
        float a = 0.f, b = 0.f;
        for (int k = 0; k < KS; ++k) { a += e0s[k]; b += e1s[k]; }
        sums[0] = a; sums[1] = b;
    }
    __syncthreads();
    if (t < KPAD) {
        wts[t]        = (t < KS) ? e0s[t] / sums[0] : 0.f;
        wts[KPAD + t] = (t < KS) ? e1s[t] / sums[1] : 0.f;
    }
    if (t == 0) {
        wts[2 * KPAD]     = expf(log_alpha[0]);
        wts[2 * KPAD + 1] = expf(log_alpha[1]);
    }
}

// ---------------------------------------------------------------------------
// Vertical blur: R4 configuration, FROZEN. R0/R3/R4 all land at ~69us; R5-R7
// proved neither wave-count (TR=8, occupancy capped ~16 waves/CU at VGPR=64),
// nor SGB scheduling, nor register rings move it -- this access pattern's
// latency floor. Loads are RAW d (linearity: blur_pad0(2d-1) =
// 2*blur_pad0.5(d)-1, the 2x-1 folded into hblur's alpha epilogue).
// ---------------------------------------------------------------------------
__device__ __forceinline__ void vblur_body_fast(const float* __restrict__ src,
                                                const float* __restrict__ g,
                                                float* __restrict__ dst,
                                                int col, int i0) {
    const float* __restrict__ p = src + (size_t)(i0 - KH) * W + col;  // row base+0
    float2 win[RING];
    float2 acc[TR];
#pragma unroll
    for (int t = 0; t < TR; ++t) acc[t] = make_float2(0.f, 0.f);
#pragma unroll
    for (int j = 0; j < RING; ++j) win[j] = *(const float2*)(p + (size_t)j * W);

    const float* __restrict__ q = p + (size_t)RING * W;   // first refill row (base+24)

    for (int m = 0; m < 3; ++m) {
#pragma unroll
        for (int r = 0; r < 24; ++r) {          // static ring indices
            const float2 nv = *(const float2*)(q + (size_t)r * W);
            SGB(SG_VMEM_READ, 1, 0);
            const float gk = g[m * 24 + r];     // uniform -> s_load
#pragma unroll
            for (int t = 0; t < TR; ++t) {
                const int w = (r + t) < 24 ? (r + t) : (r + t - 24);
                acc[t].x = fmaf(gk, win[w].x, acc[t].x);
                acc[t].y = fmaf(gk, win[w].y, acc[t].y);
            }
            SGB(SG_VALU, 36, 0);
            win[r] = nv;
        }
        q += (size_t)24 * W;
    }
    {
#pragma unroll
        for (int r = 0; r < 24; ++r) {          // taps 72..95
            float2 nv;
            if (r <= 15) {
                nv = *(const float2*)(q + (size_t)r * W);
                SGB(SG_VMEM_READ, 1, 0);
            }
            const float gk = g[72 + r];
#pragma unroll
            for (int t = 0; t < TR; ++t) {
                const int w = (r + t) < 24 ? (r + t) : (r + t - 24);
                acc[t].x = fmaf(gk, win[w].x, acc[t].x);
                acc[t].y = fmaf(gk, win[w].y, acc[t].y);
            }
            SGB(SG_VALU, 36, 0);
            if (r <= 15)
                win[r] = nv;
        }
    }
    {
        const float gk = g[96];
#pragma unroll
        for (int t = 0; t < TR; ++t) {
            acc[t].x = fmaf(gk, win[t].x, acc[t].x);
            acc[t].y = fmaf(gk, win[t].y, acc[t].y);
        }
    }
#pragma unroll
    for (int t = 0; t < TR; ++t)
        *(float2*)(dst + (size_t)(i0 + t) * W + col) = acc[t];
}

// Guarded boundary variant (6/128 strips per channel-colband).
__device__ __forceinline__ float2 vload_row_g(const float* __restrict__ src, int row, int col) {
    float2 v = make_float2(0.5f, 0.5f);       // 0.5-pad == zero-pad of (2d-1)
    if ((unsigned)row < (unsigned)H)
        v = *(const float2*)(src + (size_t)row * W + col);
    return v;
}

__device__ __forceinline__ void vblur_body_guard(const float* __restrict__ src,
                                                 const float* __restrict__ g,
                                                 float* __restrict__ dst,
                                                 int col, int i0) {
    const int base = i0 - KH;
    float2 win[RING];
    float2 acc[TR];
#pragma unroll
    for (int t = 0; t < TR; ++t) acc[t] = make_float2(0.f, 0.f);
#pragma unroll
    for (int j = 0; j < RING; ++j) win[j] = vload_row_g(src, base + j, col);

    for (int m = 0; m < 3; ++m) {
        const int kb = m * 24;
#pragma unroll
        for (int r = 0; r < 24; ++r) {
            const float gk = g[kb + r];
#pragma unroll
            for (int t = 0; t < TR; ++t) {
                const int w = (r + t) < 24 ? (r + t) : (r + t - 24);
                acc[t].x = fmaf(gk, win[w].x, acc[t].x);
                acc[t].y = fmaf(gk, win[w].y, acc[t].y);
            }
            win[r] = vload_row_g(src, base + kb + r + 24, col);
        }
    }
    {
#pragma unroll
        for (int r = 0; r < 24; ++r) {
            const float gk = g[72 + r];
#pragma unroll
            for (int t = 0; t < TR; ++t) {
                const int w = (r + t) < 24 ? (r + t) : (r + t - 24);
                acc[t].x = fmaf(gk, win[w].x, acc[t].x);
                acc[t].y = fmaf(gk, win[w].y, acc[t].y);
            }
            if (r <= 15)
                win[r] = vload_row_g(src, base + 96 + r, col);
        }
    }
    {
        const float gk = g[96];
#pragma unroll
        for (int t = 0; t < TR; ++t) {
            acc[t].x = fmaf(gk, win[t].x, acc[t].x);
            acc[t].y = fmaf(gk, win[t].y, acc[t].y);
        }
    }
#pragma unroll
    for (int t = 0; t < TR; ++t)
        *(float2*)(dst + (size_t)(i0 + t) * W + col) = acc[t];
}

// ---------------------------------------------------------------------------
// Fused kernel (R4 exact): blocks [0,1024) vblur (XCD y-band swizzle),
// blocks [1024,5120) pack image+mask -> f16 h4v (4 px/thread).
// ---------------------------------------------------------------------------
__global__ __launch_bounds__(256, 4) void pv_k(const float* __restrict__ drand,
                                               const float* __restrict__ wts,
                                               const float* __restrict__ image,
                                               const float* __restrict__ mask,
                                               float* __restrict__ tmp,
                                               h4v* __restrict__ packed) {
    const size_t HW = (size_t)H * W;
    const int bid = blockIdx.x;
    if (bid < NB_VB) {
        const int c   = bid >> 9;          // 512 blocks per channel
        const int id  = bid & 511;
        const int xcd = id & 7;            // XCD-band swizzle
        const int seq = id >> 3;
        const int yb  = xcd * 16 + (seq >> 2);
        const int xb  = seq & 3;
        const int col = (xb * 256 + threadIdx.x) * 2;
        const int i0  = yb * TR;
        const float* __restrict__ src = drand + (size_t)c * HW;
        const float* __restrict__ g   = wts + c * KPAD;
        float* __restrict__ dst       = tmp + (size_t)c * HW;
        if (i0 >= KH && i0 + 63 <= H - 1)
            vblur_body_fast(src, g, dst, col, i0);
        else
            vblur_body_guard(src, g, dst, col, i0);
    } else {
        const size_t idx4 = ((size_t)(bid - NB_VB) * 256 + threadIdx.x) * 4;
        const float4 p0 = *(const float4*)(image + idx4);
        const float4 p1 = *(const float4*)(image + HW + idx4);
        const float4 p2 = *(const float4*)(image + 2 * HW + idx4);
        const float4 pm = *(const float4*)(mask + idx4);
        h8v lo, hi;
        lo[0] = (_Float16)p0.x; lo[1] = (_Float16)p1.x; lo[2] = (_Float16)p2.x; lo[3] = (_Float16)pm.x;
        lo[4] = (_Float16)p0.y; lo[5] = (_Float16)p1.y; lo[6] = (_Float16)p2.y; lo[7] = (_Float16)pm.y;
        hi[0] = (_Float16)p0.z; hi[1] = (_Float16)p1.z; hi[2] = (_Float16)p2.z; hi[3] = (_Float16)pm.z;
        hi[4] = (_Float16)p0.w; hi[5] = (_Float16)p1.w; hi[6] = (_Float16)p2.w; hi[7] = (_Float16)pm.w;
        *(h8v*)(packed + idx4)     = lo;
        *(h8v*)(packed + idx4 + 2) = hi;
    }
}

// ---------------------------------------------------------------------------
// Kernel 2, R9: back to the PROVEN 512-thread x 4-px geometry (R7 layout:
// dense 16B/lane stores -> no write amplification; 16B lane stride in LDS ->
// 0 bank conflicts), keeping R8's one clean win: taps via SCALAR loads from
// the uniform wts pointer (s_load_dwordx4) instead of 52 broadcast
// ds_read_b128 + lgkm waits glued into the FMA stream. R8's 8px/256thr
// variant cost +13us from 2x NT-store write amplification (WRITE 131MB) and
// 16-way LDS conflicts (1.8M) -- both structural to the 32B lane stride.
// tmp is the RAW-field blur with 0.5 padding; the reference's 2x-1 is folded
// into the alpha scale: dyc = 2*a0*dy - a0. Bilinear gather from f16 packed.
// Reference quirk: x-coordinate += dy (channel 0), y-coordinate += dx.
// ---------------------------------------------------------------------------
#define SW 2160     // LDS span: need idx <= 2155; mult of 4
template <bool PACKED>
__global__ __launch_bounds__(512) void hblur_sample_k(const float* __restrict__ tmp,
                                                      const float* __restrict__ wts,
                                                      const float* __restrict__ image,
                                                      const float* __restrict__ mask,
                                                      const h4v* __restrict__ packed,
                                                      float* __restrict__ out) {
    // XCD band swizzle: XCD k walks rows [256k, 256k+256) in order, so the
    // gather window stays in that XCD's L2.
    const int i   = (blockIdx.x & 7) * 256 + (blockIdx.x >> 3);
    const int tid = threadIdx.x;

    __shared__ __align__(16) float s0[SW];
    __shared__ __align__(16) float s1[SW];

    const float* __restrict__ t0 = tmp + (size_t)i * W;
    const float* __restrict__ t1 = tmp + (size_t)H * W + (size_t)i * W;
    for (int idx = tid; idx < SW / 4; idx += 512) {
        const int colb = idx * 4 - KH;        // 16B aligned; all-in or all-out
        float4 v0 = make_float4(0.5f, 0.5f, 0.5f, 0.5f);   // 0.5-pad (raw field)
        float4 v1 = v0;
        if (colb >= 0 && colb + 3 < W) {
            v0 = *(const float4*)(t0 + colb);
            v1 = *(const float4*)(t1 + colb);
        }
        *(float4*)(s0 + idx * 4) = v0;
        *(float4*)(s1 + idx * 4) = v1;
    }
    __syncthreads();

    const int lb = tid * 4;                   // first of 4 pixels

    float4 A0 = *(const float4*)(s0 + lb), B0 = *(const float4*)(s0 + lb + 4);
    float4 A1 = *(const float4*)(s1 + lb), B1 = *(const float4*)(s1 + lb + 4);
    float dy[4] = {0.f, 0.f, 0.f, 0.f}, dx[4] = {0.f, 0.f, 0.f, 0.f};

#pragma unroll
    for (int kg = 0; kg < 26; ++kg) {         // 26 groups of 4 taps (g[97..103]=0)
        const int k0 = kg * 4;
        const float4 g0q = *(const float4*)(wts + k0);          // uniform -> s_load
        const float4 g1q = *(const float4*)(wts + KPAD + k0);   // uniform -> s_load
        const float4 N0  = *(const float4*)(s0 + lb + k0 + 8);
        const float4 N1  = *(const float4*)(s1 + lb + k0 + 8);
        const float e0[8] = {A0.x, A0.y, A0.z, A0.w, B0.x, B0.y, B0.z, B0.w};
        const float e1[8] = {A1.x, A1.y, A1.z, A1.w, B1.x, B1.y, B1.z, B1.w};
#pragma unroll
        for (int j = 0; j < 4; ++j) {
            const float gj0 = j == 0 ? g0q.x : j == 1 ? g0q.y : j == 2 ? g0q.z : g0q.w;
            const float gj1 = j == 0 ? g1q.x : j == 1 ? g1q.y : j == 2 ? g1q.z : g1q.w;
#pragma unroll
            for (int c = 0; c < 4; ++c) {
                dy[c] = fmaf(gj0, e0[c + j], dy[c]);
                dx[c] = fmaf(gj1, e1[c + j], dx[c]);
            }
        }
        A0 = B0; B0 = N0; A1 = B1; B1 = N1;
    }

    const float a0 = wts[2 * KPAD];
    const float a1 = wts[2 * KPAD + 1];
    const float a0x2 = a0 + a0;
    const float a1x2 = a1 + a1;
    const float step = 2.f / 2047.f;
    float res[4][4];
#pragma unroll
    for (int c = 0; c < 4; ++c) {
        const int j = lb + c;
        const float dyc = fmaf(dy[c], a0x2, -a0);  // (2*hv(d)-1)*a0, folded 2x-1
        const float dxc = fmaf(dx[c], a1x2, -a1);
        float xn = -1.f + (float)j * step + dyc;   // gx + dy  (reference quirk)
        float yn = -1.f + (float)i * step + dxc;   // gy + dx
        xn = fminf(fmaxf(xn, -1.f), 1.f);
        yn = fminf(fmaxf(yn, -1.f), 1.f);

        const float x = (xn + 1.f) * 0.5f * (float)(W - 1);
        const float y = (yn + 1.f) * 0.5f * (float)(H - 1);
        const float x0f = floorf(x), y0f = floorf(y);
        const float wx = x - x0f, wy = y - y0f;

        int x0 = (int)x0f, y0 = (int)y0f;
        int x1 = x0 + 1, y1 = y0 + 1;
        x0 = min(max(x0, 0), W - 1); x1 = min(max(x1, 0), W - 1);
        y0 = min(max(y0, 0), H - 1); y1 = min(max(y1, 0), H - 1);

        const float w00 = (1.f - wx) * (1.f - wy);
        const float w10 = wx * (1.f - wy);
        const float w01 = (1.f - wx) * wy;
        const float w11 = wx * wy;

        const size_t i00 = (size_t)y0 * W + x0;
        const size_t i10 = (size_t)y0 * W + x1;
        const size_t i01 = (size_t)y1 * W + x0;
        const size_t i11 = (size_t)y1 * W + x1;

        if (PACKED) {
            const h4v v00 = packed[i00], v10 = packed[i10];
            const h4v v01 = packed[i01], v11 = packed[i11];
            res[0][c] = (float)v00[0] * w00 + (float)v10[0] * w10 + (float)v01[0] * w01 + (float)v11[0] * w11;
            res[1][c] = (float)v00[1] * w00 + (float)v10[1] * w10 + (float)v01[1] * w01 + (float)v11[1] * w11;
            res[2][c] = (float)v00[2] * w00 + (float)v10[2] * w10 + (float)v01[2] * w01 + (float)v11[2] * w11;
            res[3][c] = (float)v00[3] * w00 + (float)v10[3] * w10 + (float)v01[3] * w01 + (float)v11[3] * w11;
        } else {
#pragma unroll
            for (int p = 0; p < 3; ++p) {
                const float* __restrict__ pl = image + (size_t)p * H * W;
                res[p][c] = pl[i00] * w00 + pl[i10] * w10 + pl[i01] * w01 + pl[i11] * w11;
            }
            res[3][c] = mask[i00] * w00 + mask[i10] * w10 + mask[i01] * w01 + mask[i11] * w11;
        }
    }

    const size_t o = (size_t)i * W + lb;
#pragma unroll
    for (int p = 0; p < 4; ++p) {
        nfloat4 v;
        v.x = res[p][0]; v.y = res[p][1]; v.z = res[p][2]; v.w = res[p][3];
        __builtin_nontemporal_store(v, (nfloat4*)(out + (size_t)p * H * W + o));
    }
}

// ---------------------------------------------------------------------------
extern "C" void kernel_launch(void* const* d_in, const int* in_sizes, int n_in,
                              void* d_out, int out_size, void* d_ws, size_t ws_size,
                              hipStream_t stream) {
    const float* image     = (const float*)d_in[0];  // (3,2048,2048)
    const float* mask      = (const float*)d_in[1];  // (1,2048,2048)
    const float* drand     = (const float*)d_in[2];  // (1,2,2048,2048)
    const float* log_sigma = (const float*)d_in[3];  // (2,)
    const float* log_alpha = (const float*)d_in[4];  // (2,)
    float* out = (float*)d_out;                      // 3*HW img ++ 1*HW mask

    const size_t HW = (size_t)H * W;
    // packed f16 (HW * 8 B) + tmp (2*HW * 4 B) + wts (256 floats)
    const bool can_pack = ws_size >= HW * 8 + 2 * HW * 4 + 1024;

    h4v* packed; float* tmp; float* wts;
    if (can_pack) {
        packed = (h4v*)d_ws;                      // 32 MB, 16B aligned
        tmp    = (float*)((char*)d_ws + HW * 8);  // 32 MB
        wts    = tmp + 2 * HW;                    // 226 floats
    } else {
        packed = nullptr;
        tmp    = (float*)d_ws;
        wts    = tmp + 2 * HW;
    }

    make_weights_k<<<1, 128, 0, stream>>>(log_sigma, log_alpha, wts);
    pv_k<<<can_pack ? (NB_VB + NB_PK) : NB_VB, 256, 0, stream>>>(drand, wts, image, mask,
                                                                 tmp, packed);
    if (can_pack)
        hblur_sample_k<true><<<H, 512, 0, stream>>>(tmp, wts, image, mask, packed, out);
    else
        hblur_sample_k<false><<<H, 512, 0, stream>>>(tmp, wts, image, mask, packed, out);
}